// Round 4
// baseline (692.481 us; speedup 1.0000x reference)
//
#include <hip/hip_runtime.h>
#include <stdint.h>

typedef _Float16 h2 __attribute__((ext_vector_type(2)));
typedef _Float16 h8 __attribute__((ext_vector_type(8)));
typedef float f32x4 __attribute__((ext_vector_type(4)));

__device__ __forceinline__ uint32_t pk_cvt(float a, float b) {
  return __builtin_bit_cast(uint32_t, __builtin_amdgcn_cvt_pkrtz(a, b));
}

__device__ __forceinline__ uint32_t dq(uint32_t t, h2 z2, h2 s2) {
  // t = two f16 (1024+n_lo, 1024+n_hi); exact integer subtract, one rounded mul
  h2 v = __builtin_bit_cast(h2, t);
  h2 w = (v - z2) * s2;
  return __builtin_bit_cast(uint32_t, w);
}

__device__ __forceinline__ uint32_t dq_lin(uint32_t u, h2 z2, h2 s2) {
  // nibbles at bits 0-3 and 4-7 of u -> linear pair (k, k+1)
  uint32_t t = (u & 0xFu) | ((u & 0xF0u) << 12) | 0x64006400u;
  return dq(t, z2, s2);
}

typedef __attribute__((address_space(1))) const uint32_t* gas_ptr;
typedef __attribute__((address_space(3))) uint32_t* las_ptr;
__device__ __forceinline__ void gll16(const _Float16* g, _Float16* l) {
  // lane i lands at l + i*16B (wave-uniform base); 16B per lane
  __builtin_amdgcn_global_load_lds((gas_ptr)g, (las_ptr)l, 16, 0, 0);
}

#define WAITVM(n) asm volatile("s_waitcnt vmcnt(" #n ")" ::: "memory")
#define WAITLGKM(n) asm volatile("s_waitcnt lgkmcnt(" #n ")" ::: "memory")
#define MEMFENCE  asm volatile("" ::: "memory")
#define SB __builtin_amdgcn_sched_barrier(0)

// ---------------- phase 1: x fp32 -> f16 (linear k order) ----------------
__global__ __launch_bounds__(256) void cvt_x_kernel(const float* __restrict__ x,
                                                    _Float16* __restrict__ xh,
                                                    size_t n) {
  size_t i = ((size_t)blockIdx.x * 256 + threadIdx.x) * 8;
  if (i >= n) return;
  float4 a = *(const float4*)(x + i);
  float4 b = *(const float4*)(x + i + 4);
  uint4 v = make_uint4(pk_cvt(a.x, a.y), pk_cvt(a.z, a.w),
                       pk_cvt(b.x, b.y), pk_cvt(b.z, b.w));
  *(uint4*)(xh + i) = v;
}

// ---- phase 2: 256x256 GEMM with FUSED int4 B-dequant (no W^T pass) -----
// A [M][K] f16 (gll-staged, 3 tiles ahead, 4-deep ring).
// B produced in-flight: per K-tile (32 k = 4 packed words x 256 cols),
// 512 threads load 2 words each (coalesced along N), dequant in regs,
// ds_write_b128 into swizzled Bs. q/zp/scale prefetched 2 tiles ahead into
// double-buffered named regs (loop unrolled x2 for static reg indexing).
// Per-wave vmcnt order per iter (sched_barrier-pinned groups):
//   [Q(t+2) x4][gllA(t+3) x2] ... WAITVM(8) confirms Q(t+1); A(t) was
//   confirmed by the WAITVM two iters back (in-order counter). Never 0
//   mid-loop. lgkm: 12 ds_reads + 2 ds_writes; LGKM(6) gates cluster0
//   (first 8 reads), LGKM(0) gates cluster1 + drains B-writes before the
//   next barrier. Ring safety: writes target buf last read 3 (A) / 2 (B)
//   tiles ago, all reads drained pre-barrier (r3-verified argument).
// LDS swizzle slot ^= (row>>1)&3 both sides (conflicts measured 0; the
// B ds_write quad map (4r + s^((r>>1)&3)) mod 8 is uniform -> no conflict).
__global__ __launch_bounds__(512, 2) void gemm_f16_fusedB(
    const _Float16* __restrict__ A, const uint32_t* __restrict__ qweight,
    const uint32_t* __restrict__ qzeros, const float* __restrict__ scales,
    const float* __restrict__ bias, float* __restrict__ out,
    int M, int N, int K) {
  __shared__ _Float16 As[4][256 * 32];
  __shared__ _Float16 Bs[4][256 * 32];

  // bijective XCD-aware block swizzle (m204 form)
  const int gx = gridDim.x, gy = gridDim.y;
  const int nwg = gx * gy;
  const int lin = blockIdx.y * gx + blockIdx.x;
  const int xcd = lin & 7, idx = lin >> 3;
  const int q8 = nwg >> 3, r8 = nwg & 7;
  const int wg = (xcd < r8 ? xcd * (q8 + 1) : r8 * (q8 + 1) + (xcd - r8) * q8) + idx;
  const int bn0 = (wg % gx) * 256;
  const int bm0 = (wg / gx) * 256;

  const int tid = threadIdx.x;
  const int lane = tid & 63;
  const int wave = tid >> 6;     // 0..7
  const int wm = wave >> 2;      // 0..1 -> 128 rows
  const int wn = wave & 3;       // 0..3 -> 64 cols

  f32x4 acc[8][4];
#pragma unroll
  for (int i = 0; i < 8; ++i)
#pragma unroll
    for (int j = 0; j < 4; ++j) acc[i][j] = (f32x4)0.f;

  // ---- A staging: wave w stages rows [32w,32w+32), 2 glls/tile ----
  const int srow = lane >> 2;                       // 0..15
  const int sslot = (lane & 3) ^ ((lane >> 3) & 3); // swizzled source slot
  const _Float16* pSa0 = A + (size_t)(bm0 + 32 * wave + srow) * K + sslot * 8;
  const _Float16* pSa1 = pSa0 + (size_t)16 * K;
  const int dst_off = wave * 1024;                  // (32*wave)*32 halfs

  // ---- B fused staging coords ----
  const int bcol = tid & 255;            // Bs row (column of W)
  const int kpo = tid >> 8;              // 0/1: this thread covers slots kpo, kpo+2
  const int ncol = bn0 + bcol;
  const int NP = N >> 3;
  const uint32_t* qbase = qweight + ncol;          // + kp*N
  const uint32_t* qzbase = qzeros + (ncol >> 3);   // + g*NP
  const float* scbase = scales + ncol;             // + g*N
  const int bw0 = bcol * 32 + ((kpo)     ^ ((bcol >> 1) & 3)) * 8;
  const int bw1 = bcol * 32 + ((kpo + 2) ^ ((bcol >> 1) & 3)) * 8;

  // ---- fragment read offsets: slot = (lane>>4) ^ ((row>>1)&3) ----
  const int fslot = ((lane >> 4) ^ ((lane >> 1) & 3)) * 8;
  const int aoff = (wm * 128 + (lane & 15)) * 32 + fslot;
  const int boff = (wn * 64 + (lane & 15)) * 32 + fslot;

  const int nt = K >> 5;  // K-tiles of 32 (dispatch guarantees nt >= 4, even)

  uint32_t qE0 = 0, qE1 = 0, qzE = 0; float scE = 0.f;
  uint32_t qO0 = 0, qO1 = 0, qzO = 0; float scO = 0.f;

#define GLLA(u) {                                                         \
    const size_t ko_ = (size_t)(u) * 32;                                  \
    _Float16* da_ = &As[(u) & 3][0] + dst_off;                            \
    gll16(pSa0 + ko_, da_);                                               \
    gll16(pSa1 + ko_, da_ + 512);                                         \
  }

#define QLOAD(SET, u) {                                                   \
    const size_t kpb_ = (size_t)(u) * 4 + kpo;                            \
    q##SET##0 = qbase[kpb_ * N];                                          \
    q##SET##1 = qbase[(kpb_ + 2) * N];                                    \
    const int g_ = (u) >> 2;                                              \
    qz##SET = qzbase[(size_t)g_ * NP];                                    \
    sc##SET = scbase[(size_t)g_ * N];                                     \
  }

#define DEQW(SET, u) {                                                    \
    int zp_ = (qz##SET >> ((ncol & 7) * 4)) & 15;                         \
    _Float16 hz_ = (_Float16)(float)(1024 + zp_ + 1);                     \
    _Float16 hs_ = (_Float16)sc##SET;                                     \
    h2 z2_ = {hz_, hz_}, s2_ = {hs_, hs_};                                \
    _Float16* bb_ = &Bs[(u) & 3][0];                                      \
    uint4 v0_ = make_uint4(dq_lin(q##SET##0, z2_, s2_),                   \
                           dq_lin(q##SET##0 >> 8, z2_, s2_),              \
                           dq_lin(q##SET##0 >> 16, z2_, s2_),             \
                           dq_lin(q##SET##0 >> 24, z2_, s2_));            \
    uint4 v1_ = make_uint4(dq_lin(q##SET##1, z2_, s2_),                   \
                           dq_lin(q##SET##1 >> 8, z2_, s2_),              \
                           dq_lin(q##SET##1 >> 16, z2_, s2_),             \
                           dq_lin(q##SET##1 >> 24, z2_, s2_));            \
    *(uint4*)(bb_ + bw0) = v0_;                                           \
    *(uint4*)(bb_ + bw1) = v1_;                                           \
  }

#define ITER_BODY(T, CS, LS)                                              \
  {                                                                       \
    __builtin_amdgcn_s_barrier();                                         \
    MEMFENCE;                                                             \
    const int buf_ = (T) & 3;                                             \
    const _Float16* Ab_ = &As[buf_][0] + aoff;                            \
    const _Float16* Bb_ = &Bs[buf_][0] + boff;                            \
    h8 bf_[4], af0_[4], af1_[4];                                          \
    _Pragma("unroll") for (int r = 0; r < 4; ++r)                         \
        bf_[r] = *(const h8*)(Bb_ + r * 512);                             \
    _Pragma("unroll") for (int r = 0; r < 4; ++r)                         \
        af0_[r] = *(const h8*)(Ab_ + r * 512);                            \
    _Pragma("unroll") for (int r = 0; r < 4; ++r)                         \
        af1_[r] = *(const h8*)(Ab_ + (4 + r) * 512);                      \
    SB;                                                                   \
    if ((T) + 2 < nt) QLOAD(LS, (T) + 2);                                 \
    SB;                                                                   \
    if ((T) + 3 < nt) GLLA((T) + 3);                                      \
    SB;                                                                   \
    if ((T) + 1 < nt) {                                                   \
      if ((T) + 4 <= nt) { WAITVM(8); }                                   \
      else if ((T) + 3 == nt) { WAITVM(6); }                              \
      else { WAITVM(0); }                                                 \
      SB;                                                                 \
      DEQW(CS, (T) + 1);                                                  \
      WAITLGKM(6);                                                        \
    } else {                                                              \
      WAITLGKM(4);                                                        \
    }                                                                     \
    SB;                                                                   \
    __builtin_amdgcn_s_setprio(1);                                        \
    _Pragma("unroll") for (int r = 0; r < 4; ++r)                         \
      _Pragma("unroll") for (int j = 0; j < 4; ++j)                       \
        acc[r][j] = __builtin_amdgcn_mfma_f32_16x16x32_f16(               \
            af0_[r], bf_[j], acc[r][j], 0, 0, 0);                         \
    __builtin_amdgcn_s_setprio(0);                                        \
    WAITLGKM(0);                                                          \
    SB;                                                                   \
    __builtin_amdgcn_s_setprio(1);                                        \
    _Pragma("unroll") for (int r = 0; r < 4; ++r)                         \
      _Pragma("unroll") for (int j = 0; j < 4; ++j)                       \
        acc[4 + r][j] = __builtin_amdgcn_mfma_f32_16x16x32_f16(           \
            af1_[r], bf_[j], acc[4 + r][j], 0, 0, 0);                     \
    __builtin_amdgcn_s_setprio(0);                                        \
  }

  // ---- prologue: A(0..2) glls interleaved with Q(0)->E, Q(1)->O ----
  // linear vm order: A0*2, QE*4, A1*2, QO*4, A2*2  (14 ops)
  GLLA(0); SB;
  QLOAD(E, 0); SB;
  GLLA(1); SB;
  QLOAD(O, 1); SB;
  GLLA(2); SB;
  WAITVM(8);      // A(0) + Q(0) confirmed; [A1,QO,A2]=8 in flight
  SB;
  DEQW(E, 0);     // B(0) -> Bs[0]
  WAITLGKM(0);    // B(0) writes drained before first barrier

  for (int t = 0; t < nt; t += 2) {
    ITER_BODY(t, O, E);        // consumes Q(t+1) [odd->O], loads Q(t+2)->E
    ITER_BODY(t + 1, E, O);    // consumes Q(t+2) [even->E], loads Q(t+3)->O
  }

  // epilogue: D[row=(lane>>4)*4+rr][col=lane&15] per 16x16 tile
  const int r0 = bm0 + wm * 128 + ((lane >> 4) << 2);
  const int c0 = bn0 + wn * 64 + (lane & 15);
#pragma unroll
  for (int j = 0; j < 4; ++j) {
    const int c = c0 + j * 16;
    const float bv = bias[c];
#pragma unroll
    for (int i = 0; i < 8; ++i) {
#pragma unroll
      for (int rr = 0; rr < 4; ++rr)
        out[(size_t)(r0 + i * 16 + rr) * N + c] = acc[i][j][rr] + bv;
    }
  }
#undef GLLA
#undef QLOAD
#undef DEQW
#undef ITER_BODY
}

// ------------------- fallback: round-2 fused kernel ---------------------
#define LDK 40
__global__ __launch_bounds__(256) void gptq_gemm_fused(
    const float* __restrict__ x, const uint32_t* __restrict__ qweight,
    const uint32_t* __restrict__ qzeros, const float* __restrict__ scales,
    const float* __restrict__ bias, float* __restrict__ out,
    int M, int N, int K) {
  __shared__ _Float16 As[128 * LDK];
  __shared__ _Float16 Bs[128 * LDK];
  const int tid = threadIdx.x, lane = tid & 63, wave = tid >> 6;
  const int wm = wave & 1, wn = wave >> 1;
  const int bn0 = blockIdx.x * 128, bm0 = blockIdx.y * 128;
  const int sr = tid >> 1, sg0 = (tid & 1) * 2;
  const float* xrow = x + (size_t)(bm0 + sr) * K + sg0 * 8;
  const int colb = bn0 + sr;
  const int groups = K >> 7, NP = N >> 3;
  f32x4 acc[4][4];
#pragma unroll
  for (int i = 0; i < 4; ++i)
#pragma unroll
    for (int j = 0; j < 4; ++j) acc[i][j] = (f32x4)0.f;
  const _Float16* Ab = As + (wm * 64 + (lane & 15)) * LDK + (lane >> 4) * 8;
  const _Float16* Bb = Bs + (wn * 64 + (lane & 15)) * LDK + (lane >> 4) * 8;
  for (int g = 0; g < groups; ++g) {
    uint32_t qz = qzeros[(size_t)g * NP + (colb >> 3)];
    int zp = (qz >> ((colb & 7) * 4)) & 15;
    float sc = scales[(size_t)g * N + colb];
    _Float16 hz = (_Float16)(float)(1024 + zp + 1);
    _Float16 hs = (_Float16)sc;
    h2 z2 = {hz, hz}, s2 = {hs, hs};
#pragma unroll
    for (int kt = 0; kt < 4; ++kt) {
      const int k0 = g * 128 + kt * 32;
      const float* xr = xrow + k0;
      float4 fa0 = *(const float4*)(xr);
      float4 fa1 = *(const float4*)(xr + 4);
      float4 fa2 = *(const float4*)(xr + 8);
      float4 fa3 = *(const float4*)(xr + 12);
      const size_t kp = (size_t)(k0 >> 3) + sg0;
      uint32_t q0 = qweight[kp * N + colb];
      uint32_t q1 = qweight[(kp + 1) * N + colb];
      __syncthreads();
      uint4 av0 = make_uint4(pk_cvt(fa0.x, fa1.x), pk_cvt(fa0.y, fa1.y),
                             pk_cvt(fa0.z, fa1.z), pk_cvt(fa0.w, fa1.w));
      uint4 av1 = make_uint4(pk_cvt(fa2.x, fa3.x), pk_cvt(fa2.y, fa3.y),
                             pk_cvt(fa2.z, fa3.z), pk_cvt(fa2.w, fa3.w));
      *(uint4*)(As + sr * LDK + sg0 * 8) = av0;
      *(uint4*)(As + sr * LDK + sg0 * 8 + 8) = av1;
      uint4 bv0 = make_uint4(dq((q0 & 0x000F000Fu) | 0x64006400u, z2, s2),
                             dq(((q0 >> 4) & 0x000F000Fu) | 0x64006400u, z2, s2),
                             dq(((q0 >> 8) & 0x000F000Fu) | 0x64006400u, z2, s2),
                             dq(((q0 >> 12) & 0x000F000Fu) | 0x64006400u, z2, s2));
      uint4 bv1 = make_uint4(dq((q1 & 0x000F000Fu) | 0x64006400u, z2, s2),
                             dq(((q1 >> 4) & 0x000F000Fu) | 0x64006400u, z2, s2),
                             dq(((q1 >> 8) & 0x000F000Fu) | 0x64006400u, z2, s2),
                             dq(((q1 >> 12) & 0x000F000Fu) | 0x64006400u, z2, s2));
      *(uint4*)(Bs + sr * LDK + sg0 * 8) = bv0;
      *(uint4*)(Bs + sr * LDK + sg0 * 8 + 8) = bv1;
      __syncthreads();
      h8 af[4], bf[4];
#pragma unroll
      for (int i = 0; i < 4; ++i) {
        af[i] = *(const h8*)(Ab + i * 16 * LDK);
        bf[i] = *(const h8*)(Bb + i * 16 * LDK);
      }
#pragma unroll
      for (int i = 0; i < 4; ++i)
#pragma unroll
        for (int j = 0; j < 4; ++j)
          acc[i][j] = __builtin_amdgcn_mfma_f32_16x16x32_f16(af[i], bf[j],
                                                             acc[i][j], 0, 0, 0);
    }
  }
  const int r0 = bm0 + wm * 64 + (lane >> 4) * 4;
  const int c0 = bn0 + wn * 64 + (lane & 15);
#pragma unroll
  for (int j = 0; j < 4; ++j) {
    const int c = c0 + j * 16;
    const float bv = bias[c];
#pragma unroll
    for (int i = 0; i < 4; ++i)
#pragma unroll
      for (int rr = 0; rr < 4; ++rr)
        out[(size_t)(r0 + i * 16 + rr) * N + c] = acc[i][j][rr] + bv;
  }
}

extern "C" void kernel_launch(void* const* d_in, const int* in_sizes, int n_in,
                              void* d_out, int out_size, void* d_ws, size_t ws_size,
                              hipStream_t stream) {
  const float* x = (const float*)d_in[0];
  const uint32_t* qweight = (const uint32_t*)d_in[1];
  const uint32_t* qzeros = (const uint32_t*)d_in[2];
  const float* scales = (const float*)d_in[3];
  const float* bias = (const float*)d_in[4];
  float* out = (float*)d_out;

  const int out_f = in_sizes[4];            // 11008
  const int groups = in_sizes[3] / out_f;   // 32
  const int in_f = groups * 128;            // 4096
  const int tokens = in_sizes[0] / in_f;    // 4096

  const size_t needA = (size_t)tokens * in_f * 2;   // xh only (33.5 MB)
  const bool fits = (tokens % 256) == 0 && (out_f % 256) == 0 &&
                    (in_f % 64) == 0 && in_f >= 128;
  if (ws_size >= needA && fits) {
    _Float16* xh = (_Float16*)d_ws;
    size_t nx = (size_t)tokens * in_f;
    cvt_x_kernel<<<(nx + 2047) / 2048, 256, 0, stream>>>(x, xh, nx);

    dim3 gg(out_f / 256, tokens / 256);     // 43 x 16
    gemm_f16_fusedB<<<gg, 512, 0, stream>>>(xh, qweight, qzeros, scales, bias,
                                            out, tokens, out_f, in_f);
  } else {
    dim3 grid(out_f / 128, tokens / 128);
    gptq_gemm_fused<<<grid, 256, 0, stream>>>(x, qweight, qzeros, scales, bias,
                                              out, tokens, out_f, in_f);
  }
}

// Round 6
// 646.569 us; speedup vs baseline: 1.0710x; 1.0710x over previous
//
#include <hip/hip_runtime.h>
#include <stdint.h>

typedef _Float16 h2 __attribute__((ext_vector_type(2)));
typedef _Float16 h8 __attribute__((ext_vector_type(8)));
typedef float f32x4 __attribute__((ext_vector_type(4)));

__device__ __forceinline__ uint32_t pk_cvt(float a, float b) {
  return __builtin_bit_cast(uint32_t, __builtin_amdgcn_cvt_pkrtz(a, b));
}

__device__ __forceinline__ uint32_t dq(uint32_t t, h2 z2, h2 s2) {
  // t = two f16 (1024+n_lo, 1024+n_hi); exact integer subtract, one rounded mul
  h2 v = __builtin_bit_cast(h2, t);
  h2 w = (v - z2) * s2;
  return __builtin_bit_cast(uint32_t, w);
}

typedef __attribute__((address_space(1))) const uint32_t* gas_ptr;
typedef __attribute__((address_space(3))) uint32_t* las_ptr;
__device__ __forceinline__ void gll16(const _Float16* g, _Float16* l) {
  // lane i lands at l + i*16B (wave-uniform base); 16B per lane
  __builtin_amdgcn_global_load_lds((gas_ptr)g, (las_ptr)l, 16, 0, 0);
}

#define WAITVM(n) asm volatile("s_waitcnt vmcnt(" #n ")" ::: "memory")
#define WAITLGKM(n) asm volatile("s_waitcnt lgkmcnt(" #n ")" ::: "memory")
#define MEMFENCE  asm volatile("" ::: "memory")
#define SB __builtin_amdgcn_sched_barrier(0)

// -------- phase 1: x fp32 -> f16, PAIR order (k, k+4) per 8-block --------
// Within each 8 elements, emit [f0,f4, f1,f5, f2,f6, f3,f7]. B dequant
// uses the same order (nibble pairs at bit distance 16), so every MFMA
// k-slot pairs identical original k in A and B (dot product preserved).
__global__ __launch_bounds__(256) void cvt_x_kernel(const float* __restrict__ x,
                                                    _Float16* __restrict__ xh,
                                                    size_t n) {
  size_t i = ((size_t)blockIdx.x * 256 + threadIdx.x) * 8;
  if (i >= n) return;
  float4 a = *(const float4*)(x + i);      // f0..f3
  float4 b = *(const float4*)(x + i + 4);  // f4..f7
  uint4 v = make_uint4(pk_cvt(a.x, b.x), pk_cvt(a.y, b.y),
                       pk_cvt(a.z, b.z), pk_cvt(a.w, b.w));
  *(uint4*)(xh + i) = v;
}

// ---- phase 2: 256x256 GEMM with FUSED int4 B-dequant (no W^T pass) -----
// A [M][K] f16 pair-order (gll-staged, 3 tiles ahead, 4-deep ring).
// B produced in-flight: per K-tile, 512 threads load 2 qweight words each
// (coalesced along N), dequant in regs with the pair trick (v_and_or +
// pk_sub + pk_mul per 2 elems, no repack shifts), ds_write_b128 into
// swizzled Bs. Q prefetched 2 tiles ahead (E/O named-reg double buffer).
// Pins: ONLY the counted WAITVM (compiler-invisible gll->LDS dep) and the
// trailing WAITLGKM(0) (ds_write visibility before next barrier). DEQW
// sits UNPINNED between the MFMA clusters so the compiler interleaves the
// dequant VALU into the MFMA issue shadow (m114 co-issue; r4's sched_barrier
// walls serialized it = the 375->502 regression).
// vm schedule per iter (6 ops: Q x4 then gllA x2): WAITVM(8) drains
// Q(t+1) and A(t+1) under any intra-iter order. Never 0 mid-loop.
// Ring safety: A-write targets buf read last iter (reads drained by
// trailing LGKM(0)+barrier); B-write targets buf read 3 iters ago.
// LDS swizzle slot ^= (row>>1)&3 both sides (conflicts measured 0).
__global__ __launch_bounds__(512, 2) void gemm_f16_fusedB(
    const _Float16* __restrict__ A, const uint32_t* __restrict__ qweight,
    const uint32_t* __restrict__ qzeros, const float* __restrict__ scales,
    const float* __restrict__ bias, float* __restrict__ out,
    int M, int N, int K) {
  __shared__ _Float16 As[4][256 * 32];
  __shared__ _Float16 Bs[4][256 * 32];

  // bijective XCD-aware block swizzle (m204 form)
  const int gx = gridDim.x, gy = gridDim.y;
  const int nwg = gx * gy;
  const int lin = blockIdx.y * gx + blockIdx.x;
  const int xcd = lin & 7, idx = lin >> 3;
  const int q8 = nwg >> 3, r8 = nwg & 7;
  const int wg = (xcd < r8 ? xcd * (q8 + 1) : r8 * (q8 + 1) + (xcd - r8) * q8) + idx;
  const int bn0 = (wg % gx) * 256;
  const int bm0 = (wg / gx) * 256;

  const int tid = threadIdx.x;
  const int lane = tid & 63;
  const int wave = tid >> 6;     // 0..7
  const int wm = wave >> 2;      // 0..1 -> 128 rows
  const int wn = wave & 3;       // 0..3 -> 64 cols

  f32x4 acc[8][4];
#pragma unroll
  for (int i = 0; i < 8; ++i)
#pragma unroll
    for (int j = 0; j < 4; ++j) acc[i][j] = (f32x4)0.f;

  // ---- A staging: wave w stages rows [32w,32w+32), 2 glls/tile ----
  const int srow = lane >> 2;                       // 0..15
  const int sslot = (lane & 3) ^ ((lane >> 3) & 3); // swizzled source slot
  const _Float16* pSa0 = A + (size_t)(bm0 + 32 * wave + srow) * K + sslot * 8;
  const _Float16* pSa1 = pSa0 + (size_t)16 * K;
  const int dst_off = wave * 1024;                  // (32*wave)*32 halfs

  // ---- B fused staging coords ----
  const int bcol = tid & 255;            // Bs row (column of W)
  const int kpo = tid >> 8;              // 0/1: this thread covers slots kpo, kpo+2
  const int ncol = bn0 + bcol;
  const int NP = N >> 3;
  const int zshift = (ncol & 7) * 4;
  const uint32_t* qbase = qweight + ncol;          // + kp*N
  const uint32_t* qzbase = qzeros + (ncol >> 3);   // + g*NP
  const float* scbase = scales + ncol;             // + g*N
  const int bw0 = bcol * 32 + ((kpo)     ^ ((bcol >> 1) & 3)) * 8;
  const int bw1 = bcol * 32 + ((kpo + 2) ^ ((bcol >> 1) & 3)) * 8;

  // ---- fragment read offsets: slot = (lane>>4) ^ ((row>>1)&3) ----
  const int fslot = ((lane >> 4) ^ ((lane >> 1) & 3)) * 8;
  const int aoff = (wm * 128 + (lane & 15)) * 32 + fslot;
  const int boff = (wn * 64 + (lane & 15)) * 32 + fslot;

  const int nt = K >> 5;  // K-tiles of 32 (dispatch guarantees nt >= 4, even)

  uint32_t qE0 = 0, qE1 = 0, qzE = 0; float scE = 0.f;
  uint32_t qO0 = 0, qO1 = 0, qzO = 0; float scO = 0.f;

#define GLLA(u) {                                                         \
    const size_t ko_ = (size_t)(u) * 32;                                  \
    _Float16* da_ = &As[(u) & 3][0] + dst_off;                            \
    gll16(pSa0 + ko_, da_);                                               \
    gll16(pSa1 + ko_, da_ + 512);                                         \
  }

#define QLOAD(SET, u) {                                                   \
    const size_t kpb_ = (size_t)(u) * 4 + kpo;                            \
    q##SET##0 = qbase[kpb_ * N];                                          \
    q##SET##1 = qbase[(kpb_ + 2) * N];                                    \
    const int g_ = (u) >> 2;                                              \
    qz##SET = qzbase[(size_t)g_ * NP];                                    \
    sc##SET = scbase[(size_t)g_ * N];                                     \
  }

#define DEQW(SET, u) {                                                    \
    int zp_ = (qz##SET >> zshift) & 15;                                   \
    _Float16 hz_ = (_Float16)(float)(1024 + zp_ + 1);                     \
    _Float16 hs_ = (_Float16)sc##SET;                                     \
    h2 z2_ = {hz_, hz_}, s2_ = {hs_, hs_};                                \
    _Float16* bb_ = &Bs[(u) & 3][0];                                      \
    uint4 v0_ = make_uint4(                                               \
        dq((q##SET##0 & 0x000F000Fu) | 0x64006400u, z2_, s2_),            \
        dq(((q##SET##0 >> 4) & 0x000F000Fu) | 0x64006400u, z2_, s2_),     \
        dq(((q##SET##0 >> 8) & 0x000F000Fu) | 0x64006400u, z2_, s2_),     \
        dq(((q##SET##0 >> 12) & 0x000F000Fu) | 0x64006400u, z2_, s2_));   \
    uint4 v1_ = make_uint4(                                               \
        dq((q##SET##1 & 0x000F000Fu) | 0x64006400u, z2_, s2_),            \
        dq(((q##SET##1 >> 4) & 0x000F000Fu) | 0x64006400u, z2_, s2_),     \
        dq(((q##SET##1 >> 8) & 0x000F000Fu) | 0x64006400u, z2_, s2_),     \
        dq(((q##SET##1 >> 12) & 0x000F000Fu) | 0x64006400u, z2_, s2_));   \
    *(uint4*)(bb_ + bw0) = v0_;                                           \
    *(uint4*)(bb_ + bw1) = v1_;                                           \
  }

#define ITER_BODY(T, CS, LS)                                              \
  {                                                                       \
    __builtin_amdgcn_s_barrier();                                         \
    MEMFENCE;                                                             \
    const int buf_ = (T) & 3;                                             \
    const _Float16* Ab_ = &As[buf_][0] + aoff;                            \
    const _Float16* Bb_ = &Bs[buf_][0] + boff;                            \
    h8 bf_[4], af0_[4], af1_[4];                                          \
    _Pragma("unroll") for (int r = 0; r < 4; ++r)                         \
        bf_[r] = *(const h8*)(Bb_ + r * 512);                             \
    _Pragma("unroll") for (int r = 0; r < 4; ++r)                         \
        af0_[r] = *(const h8*)(Ab_ + r * 512);                            \
    _Pragma("unroll") for (int r = 0; r < 4; ++r)                         \
        af1_[r] = *(const h8*)(Ab_ + (4 + r) * 512);                      \
    if ((T) + 2 < nt) QLOAD(LS, (T) + 2);                                 \
    if ((T) + 3 < nt) GLLA((T) + 3);                                      \
    if ((T) + 4 <= nt) { WAITVM(8); }                                     \
    else if ((T) + 3 == nt) { WAITVM(6); }                                \
    else if ((T) + 2 == nt) { WAITVM(0); }                                \
    /* (T)+1==nt: nothing outstanding */                                  \
    __builtin_amdgcn_s_setprio(1);                                        \
    _Pragma("unroll") for (int r = 0; r < 4; ++r)                         \
      _Pragma("unroll") for (int j = 0; j < 4; ++j)                       \
        acc[r][j] = __builtin_amdgcn_mfma_f32_16x16x32_f16(               \
            af0_[r], bf_[j], acc[r][j], 0, 0, 0);                         \
    if ((T) + 1 < nt) DEQW(CS, (T) + 1);                                  \
    _Pragma("unroll") for (int r = 0; r < 4; ++r)                         \
      _Pragma("unroll") for (int j = 0; j < 4; ++j)                       \
        acc[4 + r][j] = __builtin_amdgcn_mfma_f32_16x16x32_f16(           \
            af1_[r], bf_[j], acc[4 + r][j], 0, 0, 0);                     \
    __builtin_amdgcn_s_setprio(0);                                        \
    WAITLGKM(0);                                                          \
    SB;                                                                   \
  }

  // ---- prologue: A(0..2) glls interleaved with Q(0)->E, Q(1)->O ----
  // linear vm order: A0*2, QE*4, A1*2, QO*4, A2*2  (14 ops)
  GLLA(0); SB;
  QLOAD(E, 0); SB;
  GLLA(1); SB;
  QLOAD(O, 1); SB;
  GLLA(2); SB;
  WAITVM(8);      // A(0) + Q(0) confirmed; [A1,QO,A2]=8 in flight
  SB;
  DEQW(E, 0);     // B(0) -> Bs[0]
  WAITLGKM(0);    // B(0) writes drained before first barrier

  for (int t = 0; t < nt; t += 2) {
    ITER_BODY(t, O, E);        // consumes Q(t+1) [odd->O], loads Q(t+2)->E
    ITER_BODY(t + 1, E, O);    // consumes Q(t+2) [even->E], loads Q(t+3)->O
  }

  // epilogue: D[row=(lane>>4)*4+rr][col=lane&15] per 16x16 tile
  const int r0 = bm0 + wm * 128 + ((lane >> 4) << 2);
  const int c0 = bn0 + wn * 64 + (lane & 15);
#pragma unroll
  for (int j = 0; j < 4; ++j) {
    const int c = c0 + j * 16;
    const float bv = bias[c];
#pragma unroll
    for (int i = 0; i < 8; ++i) {
#pragma unroll
      for (int rr = 0; rr < 4; ++rr)
        out[(size_t)(r0 + i * 16 + rr) * N + c] = acc[i][j][rr] + bv;
    }
  }
#undef GLLA
#undef QLOAD
#undef DEQW
#undef ITER_BODY
}

// ------------------- fallback: round-2 fused kernel ---------------------
#define LDK 40
__global__ __launch_bounds__(256) void gptq_gemm_fused(
    const float* __restrict__ x, const uint32_t* __restrict__ qweight,
    const uint32_t* __restrict__ qzeros, const float* __restrict__ scales,
    const float* __restrict__ bias, float* __restrict__ out,
    int M, int N, int K) {
  __shared__ _Float16 As[128 * LDK];
  __shared__ _Float16 Bs[128 * LDK];
  const int tid = threadIdx.x, lane = tid & 63, wave = tid >> 6;
  const int wm = wave & 1, wn = wave >> 1;
  const int bn0 = blockIdx.x * 128, bm0 = blockIdx.y * 128;
  const int sr = tid >> 1, sg0 = (tid & 1) * 2;
  const float* xrow = x + (size_t)(bm0 + sr) * K + sg0 * 8;
  const int colb = bn0 + sr;
  const int groups = K >> 7, NP = N >> 3;
  f32x4 acc[4][4];
#pragma unroll
  for (int i = 0; i < 4; ++i)
#pragma unroll
    for (int j = 0; j < 4; ++j) acc[i][j] = (f32x4)0.f;
  const _Float16* Ab = As + (wm * 64 + (lane & 15)) * LDK + (lane >> 4) * 8;
  const _Float16* Bb = Bs + (wn * 64 + (lane & 15)) * LDK + (lane >> 4) * 8;
  for (int g = 0; g < groups; ++g) {
    uint32_t qz = qzeros[(size_t)g * NP + (colb >> 3)];
    int zp = (qz >> ((colb & 7) * 4)) & 15;
    float sc = scales[(size_t)g * N + colb];
    _Float16 hz = (_Float16)(float)(1024 + zp + 1);
    _Float16 hs = (_Float16)sc;
    h2 z2 = {hz, hz}, s2 = {hs, hs};
#pragma unroll
    for (int kt = 0; kt < 4; ++kt) {
      const int k0 = g * 128 + kt * 32;
      const float* xr = xrow + k0;
      float4 fa0 = *(const float4*)(xr);
      float4 fa1 = *(const float4*)(xr + 4);
      float4 fa2 = *(const float4*)(xr + 8);
      float4 fa3 = *(const float4*)(xr + 12);
      const size_t kp = (size_t)(k0 >> 3) + sg0;
      uint32_t q0 = qweight[kp * N + colb];
      uint32_t q1 = qweight[(kp + 1) * N + colb];
      __syncthreads();
      uint4 av0 = make_uint4(pk_cvt(fa0.x, fa1.x), pk_cvt(fa0.y, fa1.y),
                             pk_cvt(fa0.z, fa1.z), pk_cvt(fa0.w, fa1.w));
      uint4 av1 = make_uint4(pk_cvt(fa2.x, fa3.x), pk_cvt(fa2.y, fa3.y),
                             pk_cvt(fa2.z, fa3.z), pk_cvt(fa2.w, fa3.w));
      *(uint4*)(As + sr * LDK + sg0 * 8) = av0;
      *(uint4*)(As + sr * LDK + sg0 * 8 + 8) = av1;
      uint4 bv0 = make_uint4(dq((q0 & 0x000F000Fu) | 0x64006400u, z2, s2),
                             dq(((q0 >> 4) & 0x000F000Fu) | 0x64006400u, z2, s2),
                             dq(((q0 >> 8) & 0x000F000Fu) | 0x64006400u, z2, s2),
                             dq(((q0 >> 12) & 0x000F000Fu) | 0x64006400u, z2, s2));
      uint4 bv1 = make_uint4(dq((q1 & 0x000F000Fu) | 0x64006400u, z2, s2),
                             dq(((q1 >> 4) & 0x000F000Fu) | 0x64006400u, z2, s2),
                             dq(((q1 >> 8) & 0x000F000Fu) | 0x64006400u, z2, s2),
                             dq(((q1 >> 12) & 0x000F000Fu) | 0x64006400u, z2, s2));
      *(uint4*)(Bs + sr * LDK + sg0 * 8) = bv0;
      *(uint4*)(Bs + sr * LDK + sg0 * 8 + 8) = bv1;
      __syncthreads();
      h8 af[4], bf[4];
#pragma unroll
      for (int i = 0; i < 4; ++i) {
        af[i] = *(const h8*)(Ab + i * 16 * LDK);
        bf[i] = *(const h8*)(Bb + i * 16 * LDK);
      }
#pragma unroll
      for (int i = 0; i < 4; ++i)
#pragma unroll
        for (int j = 0; j < 4; ++j)
          acc[i][j] = __builtin_amdgcn_mfma_f32_16x16x32_f16(af[i], bf[j],
                                                             acc[i][j], 0, 0, 0);
    }
  }
  const int r0 = bm0 + wm * 64 + (lane >> 4) * 4;
  const int c0 = bn0 + wn * 64 + (lane & 15);
#pragma unroll
  for (int j = 0; j < 4; ++j) {
    const int c = c0 + j * 16;
    const float bv = bias[c];
#pragma unroll
    for (int i = 0; i < 4; ++i)
#pragma unroll
      for (int rr = 0; rr < 4; ++rr)
        out[(size_t)(r0 + i * 16 + rr) * N + c] = acc[i][j][rr] + bv;
  }
}

extern "C" void kernel_launch(void* const* d_in, const int* in_sizes, int n_in,
                              void* d_out, int out_size, void* d_ws, size_t ws_size,
                              hipStream_t stream) {
  const float* x = (const float*)d_in[0];
  const uint32_t* qweight = (const uint32_t*)d_in[1];
  const uint32_t* qzeros = (const uint32_t*)d_in[2];
  const float* scales = (const float*)d_in[3];
  const float* bias = (const float*)d_in[4];
  float* out = (float*)d_out;

  const int out_f = in_sizes[4];            // 11008
  const int groups = in_sizes[3] / out_f;   // 32
  const int in_f = groups * 128;            // 4096
  const int tokens = in_sizes[0] / in_f;    // 4096

  const size_t needA = (size_t)tokens * in_f * 2;   // xh only (33.5 MB)
  const bool fits = (tokens % 256) == 0 && (out_f % 256) == 0 &&
                    (in_f % 64) == 0 && in_f >= 128;
  if (ws_size >= needA && fits) {
    _Float16* xh = (_Float16*)d_ws;
    size_t nx = (size_t)tokens * in_f;
    cvt_x_kernel<<<(nx + 2047) / 2048, 256, 0, stream>>>(x, xh, nx);

    dim3 gg(out_f / 256, tokens / 256);     // 43 x 16
    gemm_f16_fusedB<<<gg, 512, 0, stream>>>(xh, qweight, qzeros, scales, bias,
                                            out, tokens, out_f, in_f);
  } else {
    dim3 grid(out_f / 128, tokens / 128);
    gptq_gemm_fused<<<grid, 256, 0, stream>>>(x, qweight, qzeros, scales, bias,
                                              out, tokens, out_f, in_f);
  }
}